// Round 1
// baseline (6194.978 us; speedup 1.0000x reference)
//
#include <hip/hip_runtime.h>
#include <cmath>

// ConvLSTM2D forward: B=8, T=16, H=W=96, Cin=8, F=64 (gates 4F=256), 3x3 SAME.
// One launch per timestep; implicit-GEMM-by-FMA, fp32 baseline.

#define HTOT 96
#define WTOT 96
#define CINX 8
#define FF   64
#define G4   256
#define TH   4
#define TW   4
#define BB   8
#define TT   16
#define NCH  72            // 8 x-channels + 64 h-channels
#define PATCH_ELEMS (NCH*36)

__device__ __forceinline__ float hsig(float z) {
    return fminf(fmaxf(0.2f * z + 0.5f, 0.f), 1.f);
}

__global__ __launch_bounds__(256) void convlstm_step(
    const float* __restrict__ x, int t,
    const float* __restrict__ h_in,
    float* __restrict__ c_st,
    float* __restrict__ h_out,
    const float* __restrict__ Wx,
    const float* __restrict__ Wh,
    const float* __restrict__ bias)
{
    __shared__ float patch[PATCH_ELEMS];   // [ch][6*6], ch-major: 36 contiguous floats/ch
    __shared__ float zbuf[TH*TW*G4];       // 16 positions x 256 gate channels

    const int tid = threadIdx.x;
    const int x0 = blockIdx.x * TW;
    const int y0 = blockIdx.y * TH;
    const int bb = blockIdx.z;

    // ---- stage 6x6 halo patch, channel-major, zero-padded at borders ----
    for (int e = tid; e < PATCH_ELEMS; e += 256) {
        int c = e / 36, s = e - c * 36;
        int sy = s / 6, sx = s - sy * 6;
        int gy = y0 - 1 + sy, gx = x0 - 1 + sx;
        float v = 0.f;
        if (gy >= 0 && gy < HTOT && gx >= 0 && gx < WTOT) {
            if (c < CINX)
                v = x[(((bb*TT + t)*HTOT + gy)*WTOT + gx)*CINX + c];
            else
                v = h_in[((bb*HTOT + gy)*WTOT + gx)*FF + (c - CINX)];
        }
        patch[e] = v;
    }
    __syncthreads();

    const int f = tid;                     // gate channel 0..255
    float acc[TH*TW];
    {
        float bv = bias[f];
        #pragma unroll
        for (int p = 0; p < TH*TW; ++p) acc[p] = bv;
    }

    // ---- x-conv contribution: channels 0..7 ----
    #pragma unroll 1
    for (int c = 0; c < CINX; ++c) {
        float pr[36];
        const float4* src = reinterpret_cast<const float4*>(&patch[c*36]);
        #pragma unroll
        for (int i = 0; i < 9; ++i) {
            float4 v = src[i];
            pr[4*i+0] = v.x; pr[4*i+1] = v.y; pr[4*i+2] = v.z; pr[4*i+3] = v.w;
        }
        const float* wb = Wx + c*G4 + f;
        #pragma unroll
        for (int k = 0; k < 9; ++k) {
            int ky = k / 3, kx = k - 3*ky;
            float w = wb[(size_t)k * CINX * G4];
            #pragma unroll
            for (int py = 0; py < TH; ++py)
                #pragma unroll
                for (int px = 0; px < TW; ++px)
                    acc[py*TW + px] += pr[(py+ky)*6 + (px+kx)] * w;
        }
    }

    // ---- h-conv contribution: channels 8..71 ----
    #pragma unroll 1
    for (int c = 0; c < FF; ++c) {
        float pr[36];
        const float4* src = reinterpret_cast<const float4*>(&patch[(CINX + c)*36]);
        #pragma unroll
        for (int i = 0; i < 9; ++i) {
            float4 v = src[i];
            pr[4*i+0] = v.x; pr[4*i+1] = v.y; pr[4*i+2] = v.z; pr[4*i+3] = v.w;
        }
        const float* wb = Wh + c*G4 + f;
        #pragma unroll
        for (int k = 0; k < 9; ++k) {
            int ky = k / 3, kx = k - 3*ky;
            float w = wb[(size_t)k * FF * G4];
            #pragma unroll
            for (int py = 0; py < TH; ++py)
                #pragma unroll
                for (int px = 0; px < TW; ++px)
                    acc[py*TW + px] += pr[(py+ky)*6 + (px+kx)] * w;
        }
    }

    // ---- gate fusion: z round-trip through LDS so each thread gets i,f,g,o ----
    #pragma unroll
    for (int p = 0; p < TH*TW; ++p) zbuf[p*G4 + f] = acc[p];
    __syncthreads();

    #pragma unroll
    for (int r = 0; r < 4; ++r) {
        int item = r*256 + tid;            // item = p*64 + fch
        int p   = item >> 6;
        int fch = item & 63;
        float zi = zbuf[p*G4 +   0 + fch];
        float zf = zbuf[p*G4 +  64 + fch];
        float zg = zbuf[p*G4 + 128 + fch];
        float zo = zbuf[p*G4 + 192 + fch];
        int py = p >> 2, px = p & 3;
        int gy = y0 + py, gx = x0 + px;
        int idx = ((bb*HTOT + gy)*WTOT + gx)*FF + fch;
        float cold = c_st[idx];
        float ig = hsig(zi), fg = hsig(zf), og = hsig(zo);
        float cn = fg * cold + ig * tanhf(zg);
        c_st[idx]  = cn;
        h_out[idx] = og * tanhf(cn);
    }
}

extern "C" void kernel_launch(void* const* d_in, const int* in_sizes, int n_in,
                              void* d_out, int out_size, void* d_ws, size_t ws_size,
                              hipStream_t stream) {
    const float* x  = (const float*)d_in[0];
    const float* Wx = (const float*)d_in[1];
    const float* Wh = (const float*)d_in[2];
    const float* b  = (const float*)d_in[3];

    const size_t N = (size_t)BB * HTOT * WTOT * FF;   // 4,718,592 elements
    float* h_a = (float*)d_ws;
    float* h_b = h_a + N;
    float* c   = h_b + N;

    // ws is poisoned 0xAA before every call: zero h0 and c0 ourselves.
    hipMemsetAsync(h_a, 0, N * sizeof(float), stream);
    hipMemsetAsync(c,   0, N * sizeof(float), stream);

    dim3 grid(WTOT/TW, HTOT/TH, BB);
    for (int t = 0; t < TT; ++t) {
        const float* hin = (t & 1) ? h_b : h_a;
        float* hout = (t == TT-1) ? (float*)d_out : ((t & 1) ? h_a : h_b);
        convlstm_step<<<grid, 256, 0, stream>>>(x, t, hin, c, hout, Wx, Wh, b);
    }
}

// Round 2
// 908.358 us; speedup vs baseline: 6.8200x; 6.8200x over previous
//
#include <hip/hip_runtime.h>
#include <cmath>

// ConvLSTM2D forward, bf16 MFMA implicit GEMM.
// B=8, T=16, H=W=96, Cin=8, F=64 (4F=256 gates), 3x3 SAME, 16 sequential steps.
// Per step: GEMM M=73728, N=256, K=648 (= 9 taps * (64 h-ch) + 9 taps * (8 x-ch)).
// K-steps of 32: 18 exact for h (2/tap), 3 for x (4 taps packed per step, last padded).

#define HTOT 96
#define WTOT 96
#define CINX 8
#define FF   64
#define G4   256
#define BB   8
#define TT   16

typedef __attribute__((ext_vector_type(8))) short short8;   // 8 bf16 = 4 VGPRs
typedef __attribute__((ext_vector_type(4))) float floatx4;

union U16 { uint4 u; short8 s; };

__device__ __forceinline__ float hsig(float z) {
    return fminf(fmaxf(0.2f * z + 0.5f, 0.f), 1.f);
}

__device__ __forceinline__ ushort f2bf(float f) {            // RNE fp32->bf16
    unsigned u = __float_as_uint(f);
    u = (u + 0x7fff + ((u >> 16) & 1)) >> 16;
    return (ushort)u;
}

// ---- prep: x fp32 -> bf16 (all T at once) ----
__global__ __launch_bounds__(256) void conv_x_bf16(const float* __restrict__ x,
                                                   ushort* __restrict__ xbf, int n4) {
    int i = blockIdx.x * 256 + threadIdx.x;
    if (i >= n4) return;
    float4 v = ((const float4*)x)[i];
    ushort4 o;
    o.x = f2bf(v.x); o.y = f2bf(v.y); o.z = f2bf(v.z); o.w = f2bf(v.w);
    ((ushort4*)xbf)[i] = o;
}

// ---- prep: weights fp32 HWIO -> bf16 in B-fragment order ----
// Bp[s][nt][lane][j]:  s<18: h-part, tap=s/2, k=(s&1)*32+q*8+j -> Wh[tap][k][n]
//                      s>=18: x-part, tap=(s-18)*4+q, c=j -> Wx[tap][c][n] (tap>8 -> 0)
// n = nt*16 + (lane&15), q = lane>>4.
__global__ __launch_bounds__(256) void prep_w(const float* __restrict__ Wx,
                                              const float* __restrict__ Wh,
                                              ushort* __restrict__ Bp) {
    int idx = blockIdx.x * 256 + threadIdx.x;
    if (idx >= 21 * 16 * 64) return;
    int lane = idx & 63, nt = (idx >> 6) & 15, s = idx >> 10;
    int q = lane >> 4, col = lane & 15;
    int n = nt * 16 + col;
    ushort o[8];
    if (s < 18) {
        int tap = s >> 1;
        int cbase = (s & 1) * 32 + q * 8;
        #pragma unroll
        for (int j = 0; j < 8; ++j)
            o[j] = f2bf(Wh[((size_t)tap * FF + cbase + j) * G4 + n]);
    } else {
        int tap = (s - 18) * 4 + q;
        #pragma unroll
        for (int j = 0; j < 8; ++j)
            o[j] = (tap < 9) ? f2bf(Wx[((size_t)tap * CINX + j) * G4 + n]) : (ushort)0;
    }
    U16 u;
    #pragma unroll
    for (int j = 0; j < 8; ++j) ((ushort*)&u)[j] = o[j];
    ((uint4*)Bp)[idx] = u.u;
}

// ---- main step kernel: one 8x8 spatial tile x full N=256 per block ----
__global__ __launch_bounds__(256) void convlstm_mfma(
    const ushort* __restrict__ xbf, int t,
    const ushort* __restrict__ hin,
    ushort* __restrict__ hout,
    float* __restrict__ cst,
    const ushort* __restrict__ Bp,
    const float* __restrict__ bias,
    float* __restrict__ out, int last)
{
    __shared__ ushort hpatch[100 * 64];   // 10x10 halo, 64 h-ch, ch-contiguous
    __shared__ ushort xpatch[100 * 8];    // 10x10 halo, 8 x-ch

    const int tid = threadIdx.x;
    const int x0 = blockIdx.x * 8, y0 = blockIdx.y * 8, bb = blockIdx.z;

    // stage h halo patch (bf16), zero outside borders
    for (int i = tid; i < 800; i += 256) {
        int pos = i >> 3, part = i & 7;
        int py = pos / 10, px = pos - py * 10;
        int gy = y0 - 1 + py, gx = x0 - 1 + px;
        uint4 v = make_uint4(0, 0, 0, 0);
        if (gy >= 0 && gy < HTOT && gx >= 0 && gx < WTOT)
            v = *(const uint4*)(hin + (((size_t)(bb * HTOT + gy)) * WTOT + gx) * FF + part * 8);
        *(uint4*)(hpatch + pos * 64 + part * 8) = v;
    }
    // stage x halo patch
    for (int i = tid; i < 100; i += 256) {
        int py = i / 10, px = i - py * 10;
        int gy = y0 - 1 + py, gx = x0 - 1 + px;
        uint4 v = make_uint4(0, 0, 0, 0);
        if (gy >= 0 && gy < HTOT && gx >= 0 && gx < WTOT)
            v = *(const uint4*)(xbf + ((((size_t)bb * TT + t) * HTOT + gy) * WTOT + gx) * CINX);
        *(uint4*)(xpatch + i * 8) = v;
    }
    __syncthreads();

    const int w = tid >> 6, lane = tid & 63, q = lane >> 4, col = lane & 15;

    // per-lane spatial base for each m-tile: m = mt*16 + col -> (my,mx)
    int pos0[4];
    #pragma unroll
    for (int mt = 0; mt < 4; ++mt)
        pos0[mt] = (2 * mt + (col >> 3)) * 10 + (col & 7);

    // acc[mt][gate]; wave w covers n-tiles {g*4+w} => fch slice w*16..w*16+15 for all 4 gates
    floatx4 acc[4][4];
    #pragma unroll
    for (int g = 0; g < 4; ++g) {
        float bv = bias[g * 64 + w * 16 + col];
        #pragma unroll
        for (int mt = 0; mt < 4; ++mt)
            acc[mt][g] = (floatx4){bv, bv, bv, bv};
    }

    const uint4* Bp4 = (const uint4*)Bp;

    // ---- h-conv: 18 K-steps of 32 ----
    #pragma unroll 2
    for (int s = 0; s < 18; ++s) {
        int tap = s >> 1, khalf = s & 1;
        int dy = tap / 3, dx = tap - dy * 3;          // 0..2 each (halo offset baked in)
        U16 b4[4], a4[4];
        #pragma unroll
        for (int g = 0; g < 4; ++g)
            b4[g].u = Bp4[(s * 16 + g * 4 + w) * 64 + lane];
        #pragma unroll
        for (int mt = 0; mt < 4; ++mt)
            a4[mt].u = *(const uint4*)(hpatch + (pos0[mt] + dy * 10 + dx) * 64 + khalf * 32 + q * 8);
        #pragma unroll
        for (int mt = 0; mt < 4; ++mt)
            #pragma unroll
            for (int g = 0; g < 4; ++g)
                acc[mt][g] = __builtin_amdgcn_mfma_f32_16x16x32_bf16(a4[mt].s, b4[g].s, acc[mt][g], 0, 0, 0);
    }

    // ---- x-conv: 3 K-steps of 32 (4 taps of 8 ch each; quad q selects tap) ----
    #pragma unroll
    for (int s = 0; s < 3; ++s) {
        int tap = s * 4 + q; if (tap > 8) tap = 8;    // tap 9..11: B is zero, clamp addr
        int dy = tap / 3, dx = tap - dy * 3;
        U16 b4[4], a4[4];
        #pragma unroll
        for (int g = 0; g < 4; ++g)
            b4[g].u = Bp4[((18 + s) * 16 + g * 4 + w) * 64 + lane];
        #pragma unroll
        for (int mt = 0; mt < 4; ++mt)
            a4[mt].u = *(const uint4*)(xpatch + (pos0[mt] + dy * 10 + dx) * 8);
        #pragma unroll
        for (int mt = 0; mt < 4; ++mt)
            #pragma unroll
            for (int g = 0; g < 4; ++g)
                acc[mt][g] = __builtin_amdgcn_mfma_f32_16x16x32_bf16(a4[mt].s, b4[g].s, acc[mt][g], 0, 0, 0);
    }

    // ---- epilogue: gates fused in-register (i,f,g,o same lane, different acc) ----
    #pragma unroll
    for (int mt = 0; mt < 4; ++mt) {
        #pragma unroll
        for (int r = 0; r < 4; ++r) {
            int p = mt * 16 + q * 4 + r;              // 0..63; my=p>>3, mx=p&7
            int gy = y0 + (p >> 3), gx = x0 + (p & 7);
            size_t idx = (((size_t)(bb * HTOT + gy)) * WTOT + gx) * FF + w * 16 + col;
            float zi = acc[mt][0][r], zf = acc[mt][1][r];
            float zg = acc[mt][2][r], zo = acc[mt][3][r];
            float cold = cst[idx];
            float cn = hsig(zf) * cold + hsig(zi) * tanhf(zg);
            cst[idx] = cn;
            float hn = hsig(zo) * tanhf(cn);
            hout[idx] = f2bf(hn);
            if (last) out[idx] = hn;
        }
    }
}

extern "C" void kernel_launch(void* const* d_in, const int* in_sizes, int n_in,
                              void* d_out, int out_size, void* d_ws, size_t ws_size,
                              hipStream_t stream) {
    const float* x  = (const float*)d_in[0];
    const float* Wx = (const float*)d_in[1];
    const float* Wh = (const float*)d_in[2];
    const float* b  = (const float*)d_in[3];

    const size_t NX = (size_t)BB * TT * HTOT * WTOT * CINX;  // 9,437,184
    const size_t NH = (size_t)BB * HTOT * WTOT * FF;         // 4,718,592

    char* ws = (char*)d_ws;
    ushort* xbf  = (ushort*)ws;                 ws += NX * 2;            // 18.9 MB
    ushort* hbf0 = (ushort*)ws;                 ws += NH * 2;            //  9.4 MB
    ushort* hbf1 = (ushort*)ws;                 ws += NH * 2;            //  9.4 MB
    float*  cst  = (float*)ws;                  ws += NH * 4;            // 18.9 MB
    ushort* Bp   = (ushort*)ws;                                          // 344 KB

    // ws is poisoned each call: zero h0 and c0.
    hipMemsetAsync(hbf0, 0, NH * 2, stream);
    hipMemsetAsync(cst,  0, NH * 4, stream);

    conv_x_bf16<<<(int)((NX / 4 + 255) / 256), 256, 0, stream>>>(x, xbf, (int)(NX / 4));
    prep_w<<<(21 * 16 * 64 + 255) / 256, 256, 0, stream>>>(Wx, Wh, Bp);

    dim3 grid(WTOT / 8, HTOT / 8, BB);
    for (int t = 0; t < TT; ++t) {
        const ushort* hin = (t & 1) ? hbf1 : hbf0;
        ushort* hout      = (t & 1) ? hbf0 : hbf1;
        convlstm_mfma<<<grid, 256, 0, stream>>>(xbf, t, hin, hout, cst, Bp, b,
                                                (float*)d_out, t == TT - 1);
    }
}